// Round 4
// baseline (319.316 us; speedup 1.0000x reference)
//
#include <hip/hip_runtime.h>

// VectorQuantizer forward (VQ-VAE), MI355X/gfx950 — round 4.
// Numerics are IDENTICAL to the passing round-3 kernel (f32 serial ascending-j
// FMA chain, fl32(fl32(s1+s2_k) - 2m_k), strict-< first-index argmin,
// numpy-pairwise s1/s2). Only the codebook broadcast mechanism changed:
// LDS ds_read_b128 (the round-3 bottleneck: 51% VALUBusy, LDS-return-bound)
// -> wave-uniform s_load_dwordx16 into SGPRs on the scalar memory pipe,
// consumed directly as the 1-SGPR operand of v_fma_f32. Main loop has zero
// LDS traffic; LDS codebook gone -> occupancy 8 -> 16 waves/CU.
// Loss now uses d1A directly: |d1A - ||x-e||^2| <= ~1.5e-5 per row
// (vs loss ~= 1.0 and threshold ~1e-2) => no per-row codebook re-gather.

#define NROWS (64 * 4096)            // 262144
#define DIMS 64
#define KCODES 512
#define BLOCK 256                    // 4 waves
#define GRID (NROWS / BLOCK)         // 1024 blocks, 1 row/thread
#define WS_S2_OFF 0                  // 512 floats
#define WS_RED_OFF 4096              // GRID doubles

typedef unsigned int u16v __attribute__((ext_vector_type(16)));

// numpy pairwise sum, n=64, scalar path: 8 strided accumulators, serial in i,
// then ((r0+r1)+(r2+r3)) + ((r4+r5)+(r6+r7)).  (unchanged from round 3)
__device__ __forceinline__ float pairwise64_sq(const float4* v) {
  float a[64];
  #pragma unroll
  for (int c = 0; c < 16; ++c) {
    a[4 * c + 0] = v[c].x * v[c].x;
    a[4 * c + 1] = v[c].y * v[c].y;
    a[4 * c + 2] = v[c].z * v[c].z;
    a[4 * c + 3] = v[c].w * v[c].w;
  }
  float r0 = a[0], r1 = a[1], r2 = a[2], r3 = a[3];
  float r4 = a[4], r5 = a[5], r6 = a[6], r7 = a[7];
  #pragma unroll
  for (int i = 8; i < 64; i += 8) {
    r0 += a[i + 0]; r1 += a[i + 1]; r2 += a[i + 2]; r3 += a[i + 3];
    r4 += a[i + 4]; r5 += a[i + 5]; r6 += a[i + 6]; r7 += a[i + 7];
  }
  return ((r0 + r1) + (r2 + r3)) + ((r4 + r5) + (r6 + r7));
}

// s2_k = numpy-pairwise sum(emb_k^2), precomputed once (bit-identical to r3).
__global__ void vq_s2(const float* __restrict__ emb, float* __restrict__ s2) {
  int k = blockIdx.x * 256 + threadIdx.x;   // grid 2 x 256 = 512
  const float4* row = (const float4*)(emb + (size_t)k * DIMS);
  float4 r[16];
  #pragma unroll
  for (int c = 0; c < 16; ++c) r[c] = row[c];
  s2[k] = pairwise64_sq(r);
}

// 4 FMAs against one float4 of x, SGPR codebook elements E[j0..j0+3].
#define FMA4(E, j0, c)                                        \
  acc = fmaf(xv[c].x, __uint_as_float(E[(j0) + 0]), acc);     \
  acc = fmaf(xv[c].y, __uint_as_float(E[(j0) + 1]), acc);     \
  acc = fmaf(xv[c].z, __uint_as_float(E[(j0) + 2]), acc);     \
  acc = fmaf(xv[c].w, __uint_as_float(E[(j0) + 3]), acc);

__global__ __launch_bounds__(BLOCK) void vq_main(
    const float* __restrict__ x, const float* __restrict__ emb,
    const float* __restrict__ s2, float* __restrict__ out_idx,
    float* __restrict__ out_q, double* __restrict__ ws) {
  __shared__ int   kidx[BLOCK];
  __shared__ double red[BLOCK / 64];
  const int tid = threadIdx.x;
  const int row0 = blockIdx.x * BLOCK;
  const int r = row0 + tid;

  // ---- my row into registers ----
  float4 xv[16];
  {
    const float4* p = (const float4*)(x + (size_t)r * DIMS);
    #pragma unroll
    for (int c = 0; c < 16; ++c) xv[c] = p[c];
  }
  const float s1 = pairwise64_sq(xv);

  // ---- scan all codes; codebook rows via scalar pipe (wave-uniform) ----
  float d1 = 3.4e38f;
  int kbest = 0;
  #pragma unroll 1
  for (int k = 0; k < KCODES; ++k) {
    const float* pe = emb + (size_t)k * DIMS;   // wave-uniform address
    const float* ps = s2 + k;
    u16v e0, e1, e2, e3;
    unsigned int bku;
    asm volatile(
        "s_load_dwordx16 %0, %5, 0x0\n\t"
        "s_load_dwordx16 %1, %5, 0x40\n\t"
        "s_load_dwordx16 %2, %5, 0x80\n\t"
        "s_load_dwordx16 %3, %5, 0xc0\n\t"
        "s_load_dword    %4, %6, 0x0\n\t"
        "s_waitcnt lgkmcnt(0)"
        : "=&s"(e0), "=&s"(e1), "=&s"(e2), "=&s"(e3), "=&s"(bku)
        : "s"(pe), "s"(ps));

    float acc = 0.f;                 // SERIAL ascending-j FMA chain (as r3)
    FMA4(e0,  0, 0)  FMA4(e0,  4, 1)  FMA4(e0,  8, 2)  FMA4(e0, 12, 3)
    FMA4(e1,  0, 4)  FMA4(e1,  4, 5)  FMA4(e1,  8, 6)  FMA4(e1, 12, 7)
    FMA4(e2,  0, 8)  FMA4(e2,  4, 9)  FMA4(e2,  8, 10) FMA4(e2, 12, 11)
    FMA4(e3,  0, 12) FMA4(e3,  4, 13) FMA4(e3,  8, 14) FMA4(e3, 12, 15)

    float S = s1 + __uint_as_float(bku);  // fl32(s1 + s2_k)
    float d = fmaf(-2.0f, acc, S);        // fl32(S - 2*acc), 2*acc exact
    if (d < d1) { d1 = d; kbest = k; }    // strict <: first index wins ties
  }

  out_idx[r] = (float)kbest;
  kidx[tid] = kbest;

  // ---- loss: d1 IS ||x - e_best||^2 up to ~1.5e-5 abs (loss ~ 1.0) ----
  double lsum = (double)d1;
  #pragma unroll
  for (int off = 32; off > 0; off >>= 1) lsum += __shfl_down(lsum, off);
  if ((tid & 63) == 0) red[tid >> 6] = lsum;

  __syncthreads();

  if (tid == 0) {
    double s = 0.0;
    #pragma unroll
    for (int w = 0; w < BLOCK / 64; ++w) s += red[w];
    ws[blockIdx.x] = s;   // written every launch -> no init needed
  }

  // ---- coalesced out_q: gather codebook rows from L2 via LDS kidx ----
  const float4* emb4 = (const float4*)emb;
  float4* outq4 = (float4*)out_q;
  #pragma unroll
  for (int it = 0; it < 16; ++it) {
    int idx = it * BLOCK + tid;        // 0..4095
    int rr = idx >> 4, c = idx & 15;   // 16 consecutive lanes share one row
    float4 v = emb4[(size_t)kidx[rr] * 16 + c];
    outq4[(size_t)(row0 + rr) * 16 + c] = v;
  }
}

__global__ void vq_loss_finalize(const double* __restrict__ ws,
                                 float* __restrict__ out_loss) {
  double s = 0.0;
  for (int i = threadIdx.x; i < GRID; i += 64) s += ws[i];
  #pragma unroll
  for (int off = 32; off > 0; off >>= 1) s += __shfl_down(s, off);
  if (threadIdx.x == 0)
    *out_loss = (float)(1.25 * s / (double)((size_t)NROWS * DIMS));
}

extern "C" void kernel_launch(void* const* d_in, const int* in_sizes, int n_in,
                              void* d_out, int out_size, void* d_ws, size_t ws_size,
                              hipStream_t stream) {
  (void)in_sizes; (void)n_in; (void)out_size; (void)ws_size;
  const float* x   = (const float*)d_in[0];
  const float* emb = (const float*)d_in[1];
  float* out      = (float*)d_out;
  float* out_idx  = out;                                  // NROWS
  float* out_q    = out + NROWS;                          // NROWS*DIMS
  float* out_loss = out + NROWS + (size_t)NROWS * DIMS;   // 1
  float*  ws_s2  = (float*)((char*)d_ws + WS_S2_OFF);     // 512 floats
  double* ws_red = (double*)((char*)d_ws + WS_RED_OFF);   // GRID doubles

  vq_s2<<<2, 256, 0, stream>>>(emb, ws_s2);
  vq_main<<<GRID, BLOCK, 0, stream>>>(x, emb, ws_s2, out_idx, out_q, ws_red);
  vq_loss_finalize<<<1, 64, 0, stream>>>(ws_red, out_loss);
}

// Round 6
// 318.309 us; speedup vs baseline: 1.0032x; 1.0032x over previous
//
#include <hip/hip_runtime.h>

// VectorQuantizer forward (VQ-VAE), MI355X/gfx950 — round 6.
// Numerics IDENTICAL to passing rounds 3/4: per-(row,k) serial ascending-j
// f32 FMA chain, d = fl32(fl32(s1+s2_k) - 2*acc), strict-< first-index
// argmin, numpy-pairwise s1/s2. Codebook via wave-uniform s_load_dwordx16
// -> SGPR operand of v_fma_f32 (scalar pipe; zero LDS in main loop).
//
// Round-6 change vs round 4: __launch_bounds__(256, 4). Round 4's
// VGPR_Count=40 with 64 live xv floats proves the compiler stashed the row
// in AGPRs (~64 v_accvgpr_read per k-iteration = 2x VALU work; 337us vs
// 109us FMA floor, VALUBusy 76% mostly moves). min-4-waves/EU -> 128-VGPR
// budget -> xv stays in arch VGPRs, no moves. 4 waves/SIMD hide the ~250cy
// L2-hit SMEM latency (3x128cy of peer FMA issue per 128cy own work).

#define NROWS (64 * 4096)            // 262144
#define DIMS 64
#define KCODES 512
#define BLOCK 256                    // 4 waves
#define GRID (NROWS / BLOCK)         // 1024 blocks, 1 row/thread
#define WS_S2_OFF 0                  // 512 floats
#define WS_RED_OFF 4096              // GRID doubles

typedef unsigned int u16v __attribute__((ext_vector_type(16)));

// numpy pairwise sum, n=64, scalar path: 8 strided accumulators, serial in i,
// then ((r0+r1)+(r2+r3)) + ((r4+r5)+(r6+r7)).  (unchanged)
__device__ __forceinline__ float pairwise64_sq(const float4* v) {
  float a[64];
  #pragma unroll
  for (int c = 0; c < 16; ++c) {
    a[4 * c + 0] = v[c].x * v[c].x;
    a[4 * c + 1] = v[c].y * v[c].y;
    a[4 * c + 2] = v[c].z * v[c].z;
    a[4 * c + 3] = v[c].w * v[c].w;
  }
  float r0 = a[0], r1 = a[1], r2 = a[2], r3 = a[3];
  float r4 = a[4], r5 = a[5], r6 = a[6], r7 = a[7];
  #pragma unroll
  for (int i = 8; i < 64; i += 8) {
    r0 += a[i + 0]; r1 += a[i + 1]; r2 += a[i + 2]; r3 += a[i + 3];
    r4 += a[i + 4]; r5 += a[i + 5]; r6 += a[i + 6]; r7 += a[i + 7];
  }
  return ((r0 + r1) + (r2 + r3)) + ((r4 + r5) + (r6 + r7));
}

// s2_k = numpy-pairwise sum(emb_k^2), precomputed once (bit-identical).
__global__ void vq_s2(const float* __restrict__ emb, float* __restrict__ s2) {
  int k = blockIdx.x * 256 + threadIdx.x;   // grid 2 x 256 = 512
  const float4* row = (const float4*)(emb + (size_t)k * DIMS);
  float4 r[16];
  #pragma unroll
  for (int c = 0; c < 16; ++c) r[c] = row[c];
  s2[k] = pairwise64_sq(r);
}

// 4 FMAs against one float4 of x, SGPR codebook elements E[j0..j0+3].
#define FMA4(E, j0, c)                                        \
  acc = fmaf(xv[c].x, __uint_as_float(E[(j0) + 0]), acc);     \
  acc = fmaf(xv[c].y, __uint_as_float(E[(j0) + 1]), acc);     \
  acc = fmaf(xv[c].z, __uint_as_float(E[(j0) + 2]), acc);     \
  acc = fmaf(xv[c].w, __uint_as_float(E[(j0) + 3]), acc);

__global__ __launch_bounds__(BLOCK, 4) void vq_main(
    const float* __restrict__ x, const float* __restrict__ emb,
    const float* __restrict__ s2, float* __restrict__ out_idx,
    float* __restrict__ out_q, double* __restrict__ ws) {
  __shared__ int   kidx[BLOCK];
  __shared__ double red[BLOCK / 64];
  const int tid = threadIdx.x;
  const int row0 = blockIdx.x * BLOCK;
  const int r = row0 + tid;

  // ---- my row into registers (must stay in arch VGPRs) ----
  float4 xv[16];
  {
    const float4* p = (const float4*)(x + (size_t)r * DIMS);
    #pragma unroll
    for (int c = 0; c < 16; ++c) xv[c] = p[c];
  }
  const float s1 = pairwise64_sq(xv);

  // ---- scan all codes; codebook rows via scalar pipe (wave-uniform) ----
  float d1 = 3.4e38f;
  int kbest = 0;
  #pragma unroll 1
  for (int k = 0; k < KCODES; ++k) {
    const float* pe = emb + (size_t)k * DIMS;   // wave-uniform address
    const float* ps = s2 + k;
    u16v e0, e1, e2, e3;
    unsigned int bku;
    asm volatile(
        "s_load_dwordx16 %0, %5, 0x0\n\t"
        "s_load_dwordx16 %1, %5, 0x40\n\t"
        "s_load_dwordx16 %2, %5, 0x80\n\t"
        "s_load_dwordx16 %3, %5, 0xc0\n\t"
        "s_load_dword    %4, %6, 0x0\n\t"
        "s_waitcnt lgkmcnt(0)"
        : "=&s"(e0), "=&s"(e1), "=&s"(e2), "=&s"(e3), "=&s"(bku)
        : "s"(pe), "s"(ps));

    float acc = 0.f;                 // SERIAL ascending-j FMA chain (as r3)
    FMA4(e0,  0, 0)  FMA4(e0,  4, 1)  FMA4(e0,  8, 2)  FMA4(e0, 12, 3)
    FMA4(e1,  0, 4)  FMA4(e1,  4, 5)  FMA4(e1,  8, 6)  FMA4(e1, 12, 7)
    FMA4(e2,  0, 8)  FMA4(e2,  4, 9)  FMA4(e2,  8, 10) FMA4(e2, 12, 11)
    FMA4(e3,  0, 12) FMA4(e3,  4, 13) FMA4(e3,  8, 14) FMA4(e3, 12, 15)

    float S = s1 + __uint_as_float(bku);  // fl32(s1 + s2_k)
    float d = fmaf(-2.0f, acc, S);        // fl32(S - 2*acc), 2*acc exact
    if (d < d1) { d1 = d; kbest = k; }    // strict <: first index wins ties
  }

  out_idx[r] = (float)kbest;
  kidx[tid] = kbest;

  // ---- loss: d1 IS ||x - e_best||^2 up to ~1.5e-5 abs (loss ~ 1.0) ----
  double lsum = (double)d1;
  #pragma unroll
  for (int off = 32; off > 0; off >>= 1) lsum += __shfl_down(lsum, off);
  if ((tid & 63) == 0) red[tid >> 6] = lsum;

  __syncthreads();

  if (tid == 0) {
    double s = 0.0;
    #pragma unroll
    for (int w = 0; w < BLOCK / 64; ++w) s += red[w];
    ws[blockIdx.x] = s;   // written every launch -> no init needed
  }

  // ---- coalesced out_q: gather codebook rows from L2 via LDS kidx ----
  const float4* emb4 = (const float4*)emb;
  float4* outq4 = (float4*)out_q;
  #pragma unroll
  for (int it = 0; it < 16; ++it) {
    int idx = it * BLOCK + tid;        // 0..4095
    int rr = idx >> 4, c = idx & 15;   // 16 consecutive lanes share one row
    float4 v = emb4[(size_t)kidx[rr] * 16 + c];
    outq4[(size_t)(row0 + rr) * 16 + c] = v;
  }
}

__global__ void vq_loss_finalize(const double* __restrict__ ws,
                                 float* __restrict__ out_loss) {
  double s = 0.0;
  for (int i = threadIdx.x; i < GRID; i += 64) s += ws[i];
  #pragma unroll
  for (int off = 32; off > 0; off >>= 1) s += __shfl_down(s, off);
  if (threadIdx.x == 0)
    *out_loss = (float)(1.25 * s / (double)((size_t)NROWS * DIMS));
}

extern "C" void kernel_launch(void* const* d_in, const int* in_sizes, int n_in,
                              void* d_out, int out_size, void* d_ws, size_t ws_size,
                              hipStream_t stream) {
  (void)in_sizes; (void)n_in; (void)out_size; (void)ws_size;
  const float* x   = (const float*)d_in[0];
  const float* emb = (const float*)d_in[1];
  float* out      = (float*)d_out;
  float* out_idx  = out;                                  // NROWS
  float* out_q    = out + NROWS;                          // NROWS*DIMS
  float* out_loss = out + NROWS + (size_t)NROWS * DIMS;   // 1
  float*  ws_s2  = (float*)((char*)d_ws + WS_S2_OFF);     // 512 floats
  double* ws_red = (double*)((char*)d_ws + WS_RED_OFF);   // GRID doubles

  vq_s2<<<2, 256, 0, stream>>>(emb, ws_s2);
  vq_main<<<GRID, BLOCK, 0, stream>>>(x, emb, ws_s2, out_idx, out_q, ws_red);
  vq_loss_finalize<<<1, 64, 0, stream>>>(ws_red, out_loss);
}